// Round 3
// baseline (260.030 us; speedup 1.0000x reference)
//
#include <hip/hip_runtime.h>

// Problem constants: B=4, S=2048, D=1024, H=16, HD=64
#define SEQ  2048
#define DIM  1024
#define NH   16
#define HD   64
#define NB   4

typedef __bf16 bf16_t;
typedef bf16_t bf16x8 __attribute__((ext_vector_type(8)));
typedef bf16_t bf16x4 __attribute__((ext_vector_type(4)));
typedef float  floatx4 __attribute__((ext_vector_type(4)));

#define MFMA16(a, b, c) __builtin_amdgcn_mfma_f32_16x16x32_bf16((a), (b), (c), 0, 0, 0)

// async global->LDS, 16B per lane (LDS dest is wave-uniform base + lane*16 —
// but the GLOBAL source is per-lane, so staged CONTENT can be permuted at 16B
// granularity: pre-swizzle the source address, keep LDS dest linear).
__device__ __forceinline__ void gl_lds16(const bf16_t* g, bf16_t* l) {
    __builtin_amdgcn_global_load_lds(
        (const __attribute__((address_space(1))) void*)g,
        (__attribute__((address_space(3))) void*)l,
        16, 0, 0);
}

// ---------------------------------------------------------------------------
// prep: fused fp32->bf16 convert of x + both weight transposes (one launch)
// ---------------------------------------------------------------------------
__global__ __launch_bounds__(256) void prep(
    const float* __restrict__ x, bf16_t* __restrict__ xb,
    const float* __restrict__ wqkv, bf16_t* __restrict__ wqkvT,
    const float* __restrict__ wproj, bf16_t* __restrict__ wprojT) {
    const int bid = blockIdx.x, tid = threadIdx.x;
    if (bid < 8192) {
        const int i = (bid * 256 + tid) * 4;
        const float4 v = *(const float4*)(x + i);
        xb[i + 0] = (bf16_t)v.x;
        xb[i + 1] = (bf16_t)v.y;
        xb[i + 2] = (bf16_t)v.z;
        xb[i + 3] = (bf16_t)v.w;
        return;
    }
    __shared__ bf16_t t[32][33];
    const float* in;
    bf16_t* out;
    int R, C, bx, by;
    if (bid < 8192 + 3072) {
        const int idx = bid - 8192;
        in = wqkv; out = wqkvT; R = 1024; C = 3072;
        bx = idx % 96; by = idx / 96;
    } else {
        const int idx = bid - 11264;
        in = wproj; out = wprojT; R = 1024; C = 1024;
        bx = idx & 31; by = idx >> 5;
    }
    const int c0 = bx * 32, r0 = by * 32;
    const int tx = tid & 31, ty = tid >> 5;  // 32 x 8
#pragma unroll
    for (int i = 0; i < 32; i += 8)
        t[ty + i][tx] = (bf16_t)in[(r0 + ty + i) * C + c0 + tx];
    __syncthreads();
#pragma unroll
    for (int i = 0; i < 32; i += 8)
        out[(c0 + ty + i) * R + r0 + tx] = t[tx][ty + i];
}

// ---------------------------------------------------------------------------
// GEMM: C[M,N] = A[M,K] * Bt[N,K]^T + bias[n]   (A,Bt bf16; bias fp32)
// BK=64: 32 MFMAs per barrier pair.  8-slot K-granule swizzle: slot
// s=(g+row)&7, read slot=(h*4+quad+l15)&7 -> 2-way (free).  MODE 0 computes
// C^T (swapped MFMA operands): lane holds 4 consecutive n-cols of one m-row
// -> packed b64 LDS epilogue writes.
// MODE 0: LDS-staged epilogue -> coalesced 16B stores to
//         Q*(0.125*log2e) [b,h,s,d], K[b,h,s,d], Vt[b,h,d,s]  (bf16)
//         (log2e folded into Q so attention uses bare v_exp_f32 = exp2)
// MODE 1: fp32 C row-major (N==1024), direct coalesced stores (unswapped)
// ---------------------------------------------------------------------------
template <int MODE>
__global__ __launch_bounds__(256, 2) void gemm128(
    const bf16_t* __restrict__ A, const bf16_t* __restrict__ Bt,
    const float* __restrict__ bias, int K,
    bf16_t* __restrict__ Qo, bf16_t* __restrict__ Ko, bf16_t* __restrict__ Vo,
    float* __restrict__ Co) {
    // staging Al/Bl 128x64 each (32 KB); MODE 0 epilogue reuses as 128x136 tile
    __shared__ __align__(16) bf16_t smem[MODE == 0 ? 128 * 136 : 128 * 128];
    bf16_t* Al = smem;
    bf16_t* Bl = smem + 128 * 64;

    const int tid = threadIdx.x;
    const int m0 = blockIdx.y * 128, n0 = blockIdx.x * 128;
    const int w = tid >> 6, lane = tid & 63;
    const int l15 = lane & 15, quad = lane >> 4;
    const int wm = (w & 1) * 64, wn = (w >> 1) * 64;

    floatx4 acc[4][4] = {};

    // staging: thread t fills LDS slot (t&7) of row (t>>3)+c*32, c=0..3;
    // fetch global granule g = ((t&7)-(t>>3)) & 7  (inverse of s=(g+row)&7;
    // c*32 = 0 mod 8 so one formula serves all four chunks)
    const int g_st = ((tid & 7) - (tid >> 3)) & 7;
    const bf16_t* aptr = A + (m0 + (tid >> 3)) * K + g_st * 8;
    const bf16_t* bptr = Bt + (n0 + (tid >> 3)) * K + g_st * 8;
    bf16_t* al = Al + tid * 8;
    bf16_t* bl = Bl + tid * 8;

    for (int k0 = 0; k0 < K; k0 += 64) {
#pragma unroll
        for (int c = 0; c < 4; c++) {
            gl_lds16(aptr + (c * 32) * K, al + c * 2048);
            gl_lds16(bptr + (c * 32) * K, bl + c * 2048);
        }
        aptr += 64;
        bptr += 64;
        __syncthreads();

#pragma unroll
        for (int h = 0; h < 2; h++) {
            const int sAB = (((h << 2) + quad + (l15 & 7)) & 7) * 8;
            bf16x8 af[4], bfr[4];
#pragma unroll
            for (int i = 0; i < 4; i++)
                af[i] = *(const bf16x8*)&Al[(wm + i * 16 + l15) * 64 + sAB];
#pragma unroll
            for (int j = 0; j < 4; j++)
                bfr[j] = *(const bf16x8*)&Bl[(wn + j * 16 + l15) * 64 + sAB];
#pragma unroll
            for (int i = 0; i < 4; i++)
#pragma unroll
                for (int j = 0; j < 4; j++)
                    acc[i][j] = MODE == 0 ? MFMA16(bfr[j], af[i], acc[i][j])
                                          : MFMA16(af[i], bfr[j], acc[i][j]);
        }
        __syncthreads();
    }

    if (MODE == 0) {
        // C^T layout: row m = wm+i*16+l15 (lane-fixed), col n = wn+j*16+quad*4+r
        bf16_t* Cl = smem;
        const int which = n0 >> 10;  // 0=Q 1=K 2=V, block-uniform
        // Q scale: 1/sqrt(HD)=0.125 with log2(e) folded for exp2-softmax
        const float qs = (which == 0) ? 0.18033688f : 1.0f;
#pragma unroll
        for (int j = 0; j < 4; j++) {
            const int nc = wn + j * 16 + quad * 4;
#pragma unroll
            for (int i = 0; i < 4; i++) {
                const int mrow = wm + i * 16 + l15;
                bf16x4 pk;
#pragma unroll
                for (int r = 0; r < 4; r++)
                    pk[r] = (bf16_t)((acc[i][j][r] + bias[n0 + nc + r]) * qs);
                *(bf16x4*)&Cl[mrow * 136 + nc] = pk;
            }
        }
        __syncthreads();

        if (which < 2) {
            const int row = tid >> 1, ch = (tid & 1) << 6;
            const int m = m0 + row, b = m >> 11, s = m & 2047;
            const int h = ((n0 & 1023) >> 6) + (ch >> 6);
            bf16_t* dst = (which == 0 ? Qo : Ko) + ((size_t)(b * NH + h) * SEQ + s) * HD;
            const bf16_t* src = Cl + row * 136 + ch;
#pragma unroll
            for (int g = 0; g < 8; g++)
                *(bf16x8*)(dst + g * 8) = *(const bf16x8*)(src + g * 8);
        } else {
            const int dl = tid & 127, sh = (tid >> 7) << 6;
            const int h = ((n0 & 1023) >> 6) + (dl >> 6), d = dl & 63;
            const int b = m0 >> 11, sbase = (m0 & 2047) + sh;
            bf16_t* dst = Vo + ((size_t)(b * NH + h) * HD + d) * SEQ + sbase;
#pragma unroll
            for (int g = 0; g < 8; g++) {
                bf16x8 tv;
#pragma unroll
                for (int e = 0; e < 8; e++)
                    tv[e] = Cl[(sh + g * 8 + e) * 136 + dl];
                *(bf16x8*)(dst + g * 8) = tv;
            }
        }
    } else {
        // unswapped C: row m = wm+i*16+quad*4+r, col n = wn+j*16+l15 (coalesced)
#pragma unroll
        for (int j = 0; j < 4; j++) {
            const int n = n0 + wn + j * 16 + l15;
            const float bv = bias[n];
#pragma unroll
            for (int i = 0; i < 4; i++)
#pragma unroll
                for (int r = 0; r < 4; r++) {
                    const int m = m0 + wm + i * 16 + quad * 4 + r;
                    Co[m * 1024 + n] = acc[i][j][r] + bv;
                }
        }
    }
}

// ---------------------------------------------------------------------------
// Flash attention, causal, no-running-max, exp2-softmax (log2e folded into Q).
// ONE q-tile (128 rows) per block: grid (bh=64, y=16), qt = 15 - y so the
// big tiles dispatch first (short tail).  1024 blocks, LDS 48 KB -> 3
// blocks/CU = 3 waves/SIMD (was grid-limited to 2): round-2 counters showed
// latency-bound (MfmaUtil 20 / VALUBusy 40 / HBM 4%), so TLP is the lever.
// Per-kt DOUBLE-BUFFERED LDS staging via global_load_lds with inverse-swizzled
// global source; prefetch of kt+1 issued before proc(kt) so K/V fetch latency
// hides under 32 MFMAs + softmax; single barrier per kt.
// S^T = K*Q^T -> packed b64 P-stores, tree-reduced per-lane row-sums. Ps wave-
// private: lgkmcnt(0) wait, no barrier. id%8 == bh%8 -> each XCD's L2 holds
// 8 bh's K/V (4 MB), shared by all 16 q-tile blocks of those bh.
// ---------------------------------------------------------------------------
__global__ __launch_bounds__(256, 3) void attn1q(
    const bf16_t* __restrict__ Q, const bf16_t* __restrict__ Kg,
    const bf16_t* __restrict__ Vt, bf16_t* __restrict__ Aout) {
    __shared__ __align__(16) bf16_t Ks[2 * 64 * 64];  // [buf][key][d], granule-swizzled
    __shared__ __align__(16) bf16_t Vs[2 * 64 * 64];  // [buf][d][key], granule-swizzled
    __shared__ __align__(16) bf16_t Ps[128 * 64];     // [qrow][key],   granule-swizzled

    const int bh = blockIdx.x;
    const int qt = 15 - blockIdx.y;   // big tiles first
    const int nk = 2 * qt + 2;

    const int tid = threadIdx.x, w = tid >> 6, lane = tid & 63;
    const int l15 = lane & 15, quad = lane >> 4;
    const int b = bh >> 4, hd = bh & 15;
    const int xk = l15 & 7;

    // Q fragments (B-operand of S^T = K Q^T)
    bf16x8 aq[2][2];
#pragma unroll
    for (int i = 0; i < 2; i++) {
        const bf16_t* qr = Q + (size_t)(bh * SEQ + qt * 128 + w * 32 + i * 16 + l15) * HD;
#pragma unroll
        for (int h = 0; h < 2; h++)
            aq[i][h] = *(const bf16x8*)(qr + h * 32 + quad * 8);
    }

    floatx4 o[2][4] = {};
    float li[2] = {};

    // staging: thread t stages LDS slot (t&7) of row (t>>3) and (t>>3)+32;
    // global granule g = (t&7) ^ (row&7)  (rows 32 apart share row&7), so the
    // read-side slot formula slot = granule ^ (row&7) is satisfied with a
    // LINEAR LDS destination (tid*16B) -> global_load_lds-compatible.
    const int srow = tid >> 3;
    const int sg = (tid & 7) ^ (srow & 7);
    const bf16_t* kgl = Kg + (size_t)bh * SEQ * HD + (size_t)srow * HD + sg * 8;
    const bf16_t* vgl = Vt + (size_t)bh * HD * SEQ + (size_t)srow * SEQ + sg * 8;

    auto stage = [&](int buf, int kt) {
        const bf16_t* kp = kgl + kt * (64 * HD);
        const bf16_t* vp = vgl + kt * 64;
        bf16_t* kd = Ks + buf * 4096 + tid * 8;
        bf16_t* vd = Vs + buf * 4096 + tid * 8;
        gl_lds16(kp, kd);
        gl_lds16(kp + 32 * HD, kd + 2048);
        gl_lds16(vp, vd);
        gl_lds16(vp + 32 * SEQ, vd + 2048);
    };

    auto proc = [&](int kt, int buf) {
        const bf16_t* Ksub = Ks + buf * 4096;
        const bf16_t* Vsub = Vs + buf * 4096;
        // S^T = K Q^T : C col = qrow (l15), row = key (quad*4+r)
        bf16x8 bk[4][2];
#pragma unroll
        for (int j = 0; j < 4; j++) {
            const int n = j * 16 + l15;
#pragma unroll
            for (int h = 0; h < 2; h++)
                bk[j][h] = *(const bf16x8*)&Ksub[n * 64 + (((h * 4 + quad) ^ xk) * 8)];
        }
        floatx4 z[2][4] = {};
        __builtin_amdgcn_s_setprio(1);
#pragma unroll
        for (int i = 0; i < 2; i++)
#pragma unroll
            for (int j = 0; j < 4; j++) {
                z[i][j] = MFMA16(bk[j][0], aq[i][0], z[i][j]);
                z[i][j] = MFMA16(bk[j][1], aq[i][1], z[i][j]);
            }
        __builtin_amdgcn_s_setprio(0);
        // exp2 + causal mask + tree-reduced per-lane row-sum + packed b64 P-store
#pragma unroll
        for (int i = 0; i < 2; i++) {
            const int qbase = qt * 128 + w * 32 + i * 16;
            const int qrow_l = qbase + l15;
            const bool full = (kt * 64 + 63) <= qbase;
            const int prow = w * 32 + i * 16 + l15;
            bf16_t* pbase = Ps + prow * 64;
            const int rx = prow & 7;
#pragma unroll
            for (int j = 0; j < 4; j++) {
                const int kg0 = kt * 64 + j * 16 + quad * 4;
                bf16x4 pk;
                float es[4];
#pragma unroll
                for (int r = 0; r < 4; r++) {
                    float e = __builtin_amdgcn_exp2f(z[i][j][r]);
                    if (!full && kg0 + r > qrow_l) e = 0.f;
                    es[r] = e;
                    pk[r] = (bf16_t)e;
                }
                li[i] += (es[0] + es[1]) + (es[2] + es[3]);
                const int g = 2 * j + (quad >> 1);
                *(bf16x4*)(pbase + (((g ^ rx) << 3) | ((quad & 1) << 2))) = pk;
            }
        }
        __builtin_amdgcn_s_waitcnt(0xC07F);  // lgkmcnt(0); Ps is wave-private
        // O += P V
        bf16x8 ap[2][2];
#pragma unroll
        for (int i = 0; i < 2; i++) {
            const int row = w * 32 + i * 16 + l15;
#pragma unroll
            for (int kk = 0; kk < 2; kk++)
                ap[i][kk] = *(const bf16x8*)&Ps[row * 64 +
                                               (((kk * 4 + quad) ^ (row & 7)) << 3)];
        }
        bf16x8 bv[4][2];
#pragma unroll
        for (int j = 0; j < 4; j++) {
            const int n = j * 16 + l15;
#pragma unroll
            for (int kk = 0; kk < 2; kk++)
                bv[j][kk] = *(const bf16x8*)&Vsub[n * 64 + (((kk * 4 + quad) ^ xk) * 8)];
        }
        __builtin_amdgcn_s_setprio(1);
#pragma unroll
        for (int i = 0; i < 2; i++)
#pragma unroll
            for (int j = 0; j < 4; j++) {
                o[i][j] = MFMA16(ap[i][0], bv[j][0], o[i][j]);
                o[i][j] = MFMA16(ap[i][1], bv[j][1], o[i][j]);
            }
        __builtin_amdgcn_s_setprio(0);
    };

    stage(0, 0);
    __syncthreads();  // drains vmcnt(0): buf0 staged
    for (int kt = 0; kt < nk; ++kt) {
        const int cur = kt & 1;
        if (kt + 1 < nk) stage(cur ^ 1, kt + 1);  // async prefetch, hides under proc
        proc(kt, cur);
        // barrier: (a) all waves done reading buf[cur] (safe to overwrite next
        // iter), (b) vmcnt(0) drain publishes buf[cur^1] (loads already done)
        __syncthreads();
    }

    // ---- epilogue: reduce li across quads, redistribute, normalize, store --
#pragma unroll
    for (int i = 0; i < 2; i++) {
        float s = li[i];
        s += __shfl_xor(s, 16, 64);
        s += __shfl_xor(s, 32, 64);  // all lanes: total for qrow base+l15
#pragma unroll
        for (int r = 0; r < 4; r++) {
            const float sv = __shfl(s, quad * 4 + r, 64);
            const float inv = 1.0f / sv;
            const int srow_o = qt * 128 + w * 32 + i * 16 + quad * 4 + r;
            bf16_t* orow = Aout + (size_t)(b * SEQ + srow_o) * DIM + hd * HD;
#pragma unroll
            for (int j = 0; j < 4; j++)
                orow[j * 16 + l15] = (bf16_t)(o[i][j][r] * inv);
        }
    }
}

// ---------------------------------------------------------------------------
extern "C" void kernel_launch(void* const* d_in, const int* in_sizes, int n_in,
                              void* d_out, int out_size, void* d_ws, size_t ws_size,
                              hipStream_t stream) {
    const float* x        = (const float*)d_in[0];
    const float* c_attn_w = (const float*)d_in[2];
    const float* c_attn_b = (const float*)d_in[3];
    const float* c_proj_w = (const float*)d_in[4];
    const float* c_proj_b = (const float*)d_in[5];
    float* out = (float*)d_out;

    char* ws = (char*)d_ws;
    bf16_t* xb     = (bf16_t*)ws; ws += (size_t)NB * SEQ * DIM * 2;
    bf16_t* wqkvT  = (bf16_t*)ws; ws += (size_t)3072 * 1024 * 2;
    bf16_t* wprojT = (bf16_t*)ws; ws += (size_t)1024 * 1024 * 2;
    bf16_t* Qb  = (bf16_t*)ws; ws += (size_t)NB * NH * SEQ * HD * 2;
    bf16_t* Kb  = (bf16_t*)ws; ws += (size_t)NB * NH * SEQ * HD * 2;
    // full 16 MB: Vt must NOT overlap Ab (attn reads Vt while writing Aout)
    bf16_t* Vtb = (bf16_t*)ws; ws += (size_t)NB * NH * SEQ * HD * 2;
    bf16_t* Ab  = (bf16_t*)ws; ws += (size_t)NB * SEQ * DIM * 2;

    prep<<<12288, 256, 0, stream>>>(x, xb, c_attn_w, wqkvT, c_proj_w, wprojT);

    // qkv projection: M=8192, N=3072, K=1024
    gemm128<0><<<dim3(24, 64), 256, 0, stream>>>(xb, wqkvT, c_attn_b, 1024,
                                                 Qb, Kb, Vtb, nullptr);

    // attention: 1024 one-q-tile blocks; bh-major -> id%8 == bh%8 (XCD/L2
    // locality); y ascending = qt descending -> big tiles dispatch first
    attn1q<<<dim3(NB * NH, 16), 256, 0, stream>>>(Qb, Kb, Vtb, Ab);

    // output projection: M=8192, N=1024, K=1024, fp32 out
    gemm128<1><<<dim3(8, 64), 256, 0, stream>>>(Ab, wprojT, c_proj_b, 1024,
                                                nullptr, nullptr, nullptr, out);
}

// Round 4
// 259.069 us; speedup vs baseline: 1.0037x; 1.0037x over previous
//
#include <hip/hip_runtime.h>

// Problem constants: B=4, S=2048, D=1024, H=16, HD=64
#define SEQ  2048
#define DIM  1024
#define NH   16
#define HD   64
#define NB   4

typedef __bf16 bf16_t;
typedef bf16_t bf16x8 __attribute__((ext_vector_type(8)));
typedef bf16_t bf16x4 __attribute__((ext_vector_type(4)));
typedef float  floatx4 __attribute__((ext_vector_type(4)));

#define MFMA16(a, b, c) __builtin_amdgcn_mfma_f32_16x16x32_bf16((a), (b), (c), 0, 0, 0)

// async global->LDS, 16B per lane (LDS dest is wave-uniform base + lane*16 —
// but the GLOBAL source is per-lane, so staged CONTENT can be permuted at 16B
// granularity: pre-swizzle the source address, keep LDS dest linear).
__device__ __forceinline__ void gl_lds16(const bf16_t* g, bf16_t* l) {
    __builtin_amdgcn_global_load_lds(
        (const __attribute__((address_space(1))) void*)g,
        (__attribute__((address_space(3))) void*)l,
        16, 0, 0);
}

#define VM4 asm volatile("s_waitcnt vmcnt(4)" ::: "memory")
#define VM0 asm volatile("s_waitcnt vmcnt(0)" ::: "memory")
#define NOPS ((void)0)

// ---------------------------------------------------------------------------
// prep: fused fp32->bf16 convert of x + both weight transposes (one launch)
// ---------------------------------------------------------------------------
__global__ __launch_bounds__(256) void prep(
    const float* __restrict__ x, bf16_t* __restrict__ xb,
    const float* __restrict__ wqkv, bf16_t* __restrict__ wqkvT,
    const float* __restrict__ wproj, bf16_t* __restrict__ wprojT) {
    const int bid = blockIdx.x, tid = threadIdx.x;
    if (bid < 8192) {
        const int i = (bid * 256 + tid) * 4;
        const float4 v = *(const float4*)(x + i);
        xb[i + 0] = (bf16_t)v.x;
        xb[i + 1] = (bf16_t)v.y;
        xb[i + 2] = (bf16_t)v.z;
        xb[i + 3] = (bf16_t)v.w;
        return;
    }
    __shared__ bf16_t t[32][33];
    const float* in;
    bf16_t* out;
    int R, C, bx, by;
    if (bid < 8192 + 3072) {
        const int idx = bid - 8192;
        in = wqkv; out = wqkvT; R = 1024; C = 3072;
        bx = idx % 96; by = idx / 96;
    } else {
        const int idx = bid - 11264;
        in = wproj; out = wprojT; R = 1024; C = 1024;
        bx = idx & 31; by = idx >> 5;
    }
    const int c0 = bx * 32, r0 = by * 32;
    const int tx = tid & 31, ty = tid >> 5;  // 32 x 8
#pragma unroll
    for (int i = 0; i < 32; i += 8)
        t[ty + i][tx] = (bf16_t)in[(r0 + ty + i) * C + c0 + tx];
    __syncthreads();
#pragma unroll
    for (int i = 0; i < 32; i += 8)
        out[(c0 + ty + i) * R + r0 + tx] = t[tx][ty + i];
}

// ---------------------------------------------------------------------------
// gemm256_qkv: 256x256-tile 8-phase GEMM (T2+T3+T4+T5), QKV projection only.
// C^T = Bt * A^T via swapped MFMA operands; epilogue writes
//   Q*(0.125*log2e) [b,h,s,d], K [b,h,s,d], Vt [b,h,d,s]  (bf16).
// 8 waves (2M x 4N), wave tile 128x64, acc[8][4]; BK=64, dbuf LDS 128 KB.
// Iteration = 2 K-tiles = 8 phases; each phase: {ds_read subtile | stage one
// half-tile via global_load_lds} -> raw s_barrier -> 16 MFMA (setprio) -> bar.
// Counted vmcnt(4) ONLY at phases 4 and 8 (never 0 in the loop): stage->use
// distance derived so oldest-8-retired == next tile's 4 halves:
//   P1:A0(T1) P2:A1(T1) P3:B0(T2) P4:B1(T2)+vm4 P5:A0(T2) P6:A1(T2)
//   P7:B0(T3) P8:B1(T3)+vm4      (T1=2i+1, T2=2i+2, T3=2i+3)
// Overwrite-safety: each half region is re-staged >=1 full barrier after its
// last ds_read (B of buf read only at P1/P5; A of buf read P1-P4 / P5-P8).
// Last iteration peeled: stages A(NT-1) at P1/P2, vm0 at P4, no stages after.
// Granule swizzle: slot=(g+row)&7 (read slot=(kk*4+quad+row)&7 -> 2-way, free).
// ---------------------------------------------------------------------------
__global__ __launch_bounds__(512, 2) void gemm256_qkv(
    const bf16_t* __restrict__ A, const bf16_t* __restrict__ Bt,
    const float* __restrict__ bias, int K,
    bf16_t* __restrict__ Qo, bf16_t* __restrict__ Ko, bf16_t* __restrict__ Vo) {
    __shared__ __align__(16) bf16_t smem[65536];  // 128 KB
    bf16_t* As = smem;           // [buf][half][128][64]: buf*16384 + half*8192
    bf16_t* Bs = smem + 32768;

    // bijective XCD swizzle: 384 blocks = 8 XCDs x 48 contiguous chunks
    const int bid = blockIdx.x;
    const int swz = (bid & 7) * 48 + (bid >> 3);
    const int m0 = (swz / 12) * 256, n0 = (swz % 12) * 256;

    const int tid = threadIdx.x;
    const int w = tid >> 6, lane = tid & 63;
    const int l15 = lane & 15, quad = lane >> 4;
    const int wr = w >> 2, wc = w & 3;  // 2M x 4N wave grid
    const int xk = l15 & 7;

    floatx4 acc[8][4] = {};

    // staging: thread t -> rows (t>>3), (t>>3)+64 of a half-tile, slot t&7;
    // global granule g = ((t&7) - row) & 7  (inverse of slot=(g+row)&7)
    const int strow = tid >> 3;
    const int stg = ((tid & 7) - strow) & 7;
    const bf16_t* aA = A + (size_t)(m0 + strow) * K + stg * 8;
    const bf16_t* aB = Bt + (size_t)(n0 + strow) * K + stg * 8;

    auto stA = [&](int buf, int kt, int h) {
        const bf16_t* p = aA + ((size_t)h * 128) * K + kt * 64;
        bf16_t* d = As + buf * 16384 + h * 8192 + tid * 8;
        gl_lds16(p, d);
        gl_lds16(p + (size_t)64 * K, d + 4096);
    };
    auto stB = [&](int buf, int kt, int h) {
        const bf16_t* p = aB + ((size_t)h * 128) * K + kt * 64;
        bf16_t* d = Bs + buf * 16384 + h * 8192 + tid * 8;
        gl_lds16(p, d);
        gl_lds16(p + (size_t)64 * K, d + 4096);
    };

    // per-wave read bases: A half = wr; B half = wc>>1, quarter row (wc&1)*64
    const bf16_t* Awave0 = As + wr * 8192;
    const bf16_t* Bwave0 = Bs + (wc >> 1) * 8192 + (wc & 1) * 4096;

    bf16x8 bfr[4][2];  // B-frags persist across the 4 phases of a K-tile

#define PHASE(BUF, Q, STAGE, VMW)                                              \
    do {                                                                       \
        const bf16_t* Ab_ = Awave0 + (BUF) * 16384;                            \
        const bf16_t* Bb_ = Bwave0 + (BUF) * 16384;                            \
        if ((Q) == 0) {                                                        \
            _Pragma("unroll") for (int j_ = 0; j_ < 4; j_++)                   \
                _Pragma("unroll") for (int kk_ = 0; kk_ < 2; kk_++)            \
                    bfr[j_][kk_] = *(const bf16x8*)&Bb_[(j_ * 16 + l15) * 64 + \
                        (((kk_ * 4 + quad) + xk) & 7) * 8];                    \
        }                                                                      \
        bf16x8 af_[2][2];                                                      \
        _Pragma("unroll") for (int di_ = 0; di_ < 2; di_++)                    \
            _Pragma("unroll") for (int kk_ = 0; kk_ < 2; kk_++)                \
                af_[di_][kk_] = *(const bf16x8*)&Ab_[(((Q) * 2 + di_) * 16 + l15) * 64 + \
                    (((kk_ * 4 + quad) + xk) & 7) * 8];                        \
        STAGE;                                                                 \
        VMW;                                                                   \
        asm volatile("" ::: "memory");                                         \
        __builtin_amdgcn_s_barrier();                                          \
        asm volatile("s_waitcnt lgkmcnt(0)" ::: "memory");                     \
        __builtin_amdgcn_s_setprio(1);                                         \
        _Pragma("unroll") for (int di_ = 0; di_ < 2; di_++)                    \
            _Pragma("unroll") for (int j_ = 0; j_ < 4; j_++) {                 \
                acc[(Q) * 2 + di_][j_] =                                       \
                    MFMA16(bfr[j_][0], af_[di_][0], acc[(Q) * 2 + di_][j_]);   \
                acc[(Q) * 2 + di_][j_] =                                       \
                    MFMA16(bfr[j_][1], af_[di_][1], acc[(Q) * 2 + di_][j_]);   \
            }                                                                  \
        __builtin_amdgcn_s_setprio(0);                                         \
        asm volatile("" ::: "memory");                                         \
        __builtin_amdgcn_s_barrier();                                          \
        asm volatile("" ::: "memory");                                         \
    } while (0)

    const int NT = K >> 6;   // 16 K-tiles
    const int NI = NT >> 1;  // 8 iterations

    // prologue: t0 fully + B halves of t1 (12 loads); vm4 -> t0's 8 retired
    stA(0, 0, 0); stA(0, 0, 1); stB(0, 0, 0); stB(0, 0, 1);
    stB(1, 1, 0); stB(1, 1, 1);
    VM4;
    asm volatile("" ::: "memory");
    __builtin_amdgcn_s_barrier();
    asm volatile("" ::: "memory");

    for (int it = 0; it < NI - 1; ++it) {
        const int T1 = 2 * it + 1, T2 = 2 * it + 2, T3 = 2 * it + 3;
        PHASE(0, 0, stA(1, T1, 0), NOPS);
        PHASE(0, 1, stA(1, T1, 1), NOPS);
        PHASE(0, 2, stB(0, T2, 0), NOPS);
        PHASE(0, 3, stB(0, T2, 1), VM4);
        PHASE(1, 0, stA(0, T2, 0), NOPS);
        PHASE(1, 1, stA(0, T2, 1), NOPS);
        PHASE(1, 2, stB(1, T3, 0), NOPS);
        PHASE(1, 3, stB(1, T3, 1), VM4);
    }
    {  // peeled last iteration: tiles NT-2 (buf0), NT-1 (buf1)
        PHASE(0, 0, stA(1, NT - 1, 0), NOPS);
        PHASE(0, 1, stA(1, NT - 1, 1), NOPS);
        PHASE(0, 2, NOPS, NOPS);
        PHASE(0, 3, NOPS, VM0);
        PHASE(1, 0, NOPS, NOPS);
        PHASE(1, 1, NOPS, NOPS);
        PHASE(1, 2, NOPS, NOPS);
        PHASE(1, 3, NOPS, NOPS);
    }
#undef PHASE

    // ---- epilogue: two 128-row chunks through LDS (Et[128][264]) ----------
    bf16_t* Et = smem;
    const int which = n0 >> 10;  // 0=Q 1=K 2=V, block-uniform
    // Q scale: 1/sqrt(HD)=0.125 with log2(e) folded for exp2-softmax
    const float qs = (which == 0) ? 0.18033688f : 1.0f;
#pragma unroll
    for (int c = 0; c < 2; ++c) {
        if (c) __syncthreads();  // chunk0 reads done before overwrite
        if (wr == c) {
            // C^T: row m = i*16+l15 (lane-fixed), col n = wc*64+j*16+quad*4+r
#pragma unroll
            for (int j = 0; j < 4; j++) {
                const int nc = wc * 64 + j * 16 + quad * 4;
#pragma unroll
                for (int i = 0; i < 8; i++) {
                    const int mrow = i * 16 + l15;
                    bf16x4 pk;
#pragma unroll
                    for (int r = 0; r < 4; r++)
                        pk[r] = (bf16_t)((acc[i][j][r] + bias[n0 + nc + r]) * qs);
                    *(bf16x4*)&Et[mrow * 264 + nc] = pk;
                }
            }
        }
        __syncthreads();
        if (which < 2) {
            const int row = tid >> 2, seg = tid & 3;
            const int m = m0 + c * 128 + row, b = m >> 11, s = m & 2047;
            const int h = ((n0 & 1023) >> 6) + seg;
            bf16_t* dst = (which == 0 ? Qo : Ko) + ((size_t)(b * NH + h) * SEQ + s) * HD;
            const bf16_t* src = Et + row * 264 + seg * 64;
#pragma unroll
            for (int g = 0; g < 8; g++)
                *(bf16x8*)(dst + g * 8) = *(const bf16x8*)(src + g * 8);
        } else {
            const int line = tid >> 1, sh = (tid & 1) << 6;
            const int seg = line >> 6, d = line & 63;
            const int h = ((n0 & 1023) >> 6) + seg;
            const int b = m0 >> 11;
            const int sbase = (m0 & 2047) + c * 128 + sh;
            bf16_t* dst = Vo + ((size_t)(b * NH + h) * HD + d) * SEQ + sbase;
#pragma unroll
            for (int g = 0; g < 8; g++) {
                bf16x8 tv;
#pragma unroll
                for (int e = 0; e < 8; e++)
                    tv[e] = Et[(sh + g * 8 + e) * 264 + seg * 64 + d];
                *(bf16x8*)(dst + g * 8) = tv;
            }
        }
    }
}

// ---------------------------------------------------------------------------
// GEMM 128x128 (2-phase), used for the output projection only.
// MODE 1: fp32 C row-major (N==1024), direct coalesced stores (unswapped)
// ---------------------------------------------------------------------------
template <int MODE>
__global__ __launch_bounds__(256, 2) void gemm128(
    const bf16_t* __restrict__ A, const bf16_t* __restrict__ Bt,
    const float* __restrict__ bias, int K, float* __restrict__ Co) {
    __shared__ __align__(16) bf16_t smem[128 * 128];
    bf16_t* Al = smem;
    bf16_t* Bl = smem + 128 * 64;

    const int tid = threadIdx.x;
    const int m0 = blockIdx.y * 128, n0 = blockIdx.x * 128;
    const int w = tid >> 6, lane = tid & 63;
    const int l15 = lane & 15, quad = lane >> 4;
    const int wm = (w & 1) * 64, wn = (w >> 1) * 64;

    floatx4 acc[4][4] = {};

    const int g_st = ((tid & 7) - (tid >> 3)) & 7;
    const bf16_t* aptr = A + (m0 + (tid >> 3)) * K + g_st * 8;
    const bf16_t* bptr = Bt + (n0 + (tid >> 3)) * K + g_st * 8;
    bf16_t* al = Al + tid * 8;
    bf16_t* bl = Bl + tid * 8;

    for (int k0 = 0; k0 < K; k0 += 64) {
#pragma unroll
        for (int c = 0; c < 4; c++) {
            gl_lds16(aptr + (c * 32) * K, al + c * 2048);
            gl_lds16(bptr + (c * 32) * K, bl + c * 2048);
        }
        aptr += 64;
        bptr += 64;
        __syncthreads();

#pragma unroll
        for (int h = 0; h < 2; h++) {
            const int sAB = (((h << 2) + quad + (l15 & 7)) & 7) * 8;
            bf16x8 af[4], bfr[4];
#pragma unroll
            for (int i = 0; i < 4; i++)
                af[i] = *(const bf16x8*)&Al[(wm + i * 16 + l15) * 64 + sAB];
#pragma unroll
            for (int j = 0; j < 4; j++)
                bfr[j] = *(const bf16x8*)&Bl[(wn + j * 16 + l15) * 64 + sAB];
#pragma unroll
            for (int i = 0; i < 4; i++)
#pragma unroll
                for (int j = 0; j < 4; j++)
                    acc[i][j] = MFMA16(af[i], bfr[j], acc[i][j]);
        }
        __syncthreads();
    }

    // unswapped C: row m = wm+i*16+quad*4+r, col n = wn+j*16+l15 (coalesced)
#pragma unroll
    for (int j = 0; j < 4; j++) {
        const int n = n0 + wn + j * 16 + l15;
        const float bv = bias[n];
#pragma unroll
        for (int i = 0; i < 4; i++)
#pragma unroll
            for (int r = 0; r < 4; r++) {
                const int m = m0 + wm + i * 16 + quad * 4 + r;
                Co[m * 1024 + n] = acc[i][j][r] + bv;
            }
    }
}

// ---------------------------------------------------------------------------
// Flash attention, causal, no-running-max, exp2-softmax (log2e folded into Q).
// ONE q-tile (128 rows) per block: grid (bh=64, y=16), qt = 15 - y so the
// big tiles dispatch first (short tail).  1024 blocks, LDS 48 KB -> 3
// blocks/CU = 3 waves/SIMD.  Per-kt DOUBLE-BUFFERED LDS staging via
// global_load_lds with inverse-swizzled global source; prefetch of kt+1
// issued before proc(kt); single barrier per kt.  S^T = K*Q^T -> packed b64
// P-stores, tree-reduced per-lane row-sums.  Ps wave-private: lgkmcnt(0)
// wait, no barrier.  id%8 == bh%8 -> XCD/L2 locality on K/V.
// ---------------------------------------------------------------------------
__global__ __launch_bounds__(256, 3) void attn1q(
    const bf16_t* __restrict__ Q, const bf16_t* __restrict__ Kg,
    const bf16_t* __restrict__ Vt, bf16_t* __restrict__ Aout) {
    __shared__ __align__(16) bf16_t Ks[2 * 64 * 64];  // [buf][key][d], granule-swizzled
    __shared__ __align__(16) bf16_t Vs[2 * 64 * 64];  // [buf][d][key], granule-swizzled
    __shared__ __align__(16) bf16_t Ps[128 * 64];     // [qrow][key],   granule-swizzled

    const int bh = blockIdx.x;
    const int qt = 15 - blockIdx.y;  // big tiles first
    const int nk = 2 * qt + 2;

    const int tid = threadIdx.x, w = tid >> 6, lane = tid & 63;
    const int l15 = lane & 15, quad = lane >> 4;
    const int b = bh >> 4, hd = bh & 15;
    const int xk = l15 & 7;

    // Q fragments (B-operand of S^T = K Q^T)
    bf16x8 aq[2][2];
#pragma unroll
    for (int i = 0; i < 2; i++) {
        const bf16_t* qr = Q + (size_t)(bh * SEQ + qt * 128 + w * 32 + i * 16 + l15) * HD;
#pragma unroll
        for (int h = 0; h < 2; h++)
            aq[i][h] = *(const bf16x8*)(qr + h * 32 + quad * 8);
    }

    floatx4 o[2][4] = {};
    float li[2] = {};

    const int srow = tid >> 3;
    const int sg = (tid & 7) ^ (srow & 7);
    const bf16_t* kgl = Kg + (size_t)bh * SEQ * HD + (size_t)srow * HD + sg * 8;
    const bf16_t* vgl = Vt + (size_t)bh * HD * SEQ + (size_t)srow * SEQ + sg * 8;

    auto stage = [&](int buf, int kt) {
        const bf16_t* kp = kgl + kt * (64 * HD);
        const bf16_t* vp = vgl + kt * 64;
        bf16_t* kd = Ks + buf * 4096 + tid * 8;
        bf16_t* vd = Vs + buf * 4096 + tid * 8;
        gl_lds16(kp, kd);
        gl_lds16(kp + 32 * HD, kd + 2048);
        gl_lds16(vp, vd);
        gl_lds16(vp + 32 * SEQ, vd + 2048);
    };

    auto proc = [&](int kt, int buf) {
        const bf16_t* Ksub = Ks + buf * 4096;
        const bf16_t* Vsub = Vs + buf * 4096;
        bf16x8 bk[4][2];
#pragma unroll
        for (int j = 0; j < 4; j++) {
            const int n = j * 16 + l15;
#pragma unroll
            for (int h = 0; h < 2; h++)
                bk[j][h] = *(const bf16x8*)&Ksub[n * 64 + (((h * 4 + quad) ^ xk) * 8)];
        }
        floatx4 z[2][4] = {};
        __builtin_amdgcn_s_setprio(1);
#pragma unroll
        for (int i = 0; i < 2; i++)
#pragma unroll
            for (int j = 0; j < 4; j++) {
                z[i][j] = MFMA16(bk[j][0], aq[i][0], z[i][j]);
                z[i][j] = MFMA16(bk[j][1], aq[i][1], z[i][j]);
            }
        __builtin_amdgcn_s_setprio(0);
#pragma unroll
        for (int i = 0; i < 2; i++) {
            const int qbase = qt * 128 + w * 32 + i * 16;
            const int qrow_l = qbase + l15;
            const bool full = (kt * 64 + 63) <= qbase;
            const int prow = w * 32 + i * 16 + l15;
            bf16_t* pbase = Ps + prow * 64;
            const int rx = prow & 7;
#pragma unroll
            for (int j = 0; j < 4; j++) {
                const int kg0 = kt * 64 + j * 16 + quad * 4;
                bf16x4 pk;
                float es[4];
#pragma unroll
                for (int r = 0; r < 4; r++) {
                    float e = __builtin_amdgcn_exp2f(z[i][j][r]);
                    if (!full && kg0 + r > qrow_l) e = 0.f;
                    es[r] = e;
                    pk[r] = (bf16_t)e;
                }
                li[i] += (es[0] + es[1]) + (es[2] + es[3]);
                const int g = 2 * j + (quad >> 1);
                *(bf16x4*)(pbase + (((g ^ rx) << 3) | ((quad & 1) << 2))) = pk;
            }
        }
        __builtin_amdgcn_s_waitcnt(0xC07F);  // lgkmcnt(0); Ps is wave-private
        bf16x8 ap[2][2];
#pragma unroll
        for (int i = 0; i < 2; i++) {
            const int row = w * 32 + i * 16 + l15;
#pragma unroll
            for (int kk = 0; kk < 2; kk++)
                ap[i][kk] = *(const bf16x8*)&Ps[row * 64 +
                                               (((kk * 4 + quad) ^ (row & 7)) << 3)];
        }
        bf16x8 bv[4][2];
#pragma unroll
        for (int j = 0; j < 4; j++) {
            const int n = j * 16 + l15;
#pragma unroll
            for (int kk = 0; kk < 2; kk++)
                bv[j][kk] = *(const bf16x8*)&Vsub[n * 64 + (((kk * 4 + quad) ^ xk) * 8)];
        }
        __builtin_amdgcn_s_setprio(1);
#pragma unroll
        for (int i = 0; i < 2; i++)
#pragma unroll
            for (int j = 0; j < 4; j++) {
                o[i][j] = MFMA16(ap[i][0], bv[j][0], o[i][j]);
                o[i][j] = MFMA16(ap[i][1], bv[j][1], o[i][j]);
            }
        __builtin_amdgcn_s_setprio(0);
    };

    stage(0, 0);
    __syncthreads();  // drains vmcnt(0): buf0 staged
    for (int kt = 0; kt < nk; ++kt) {
        const int cur = kt & 1;
        if (kt + 1 < nk) stage(cur ^ 1, kt + 1);  // async prefetch under proc
        proc(kt, cur);
        __syncthreads();
    }

    // ---- epilogue: reduce li across quads, redistribute, normalize, store --
#pragma unroll
    for (int i = 0; i < 2; i++) {
        float s = li[i];
        s += __shfl_xor(s, 16, 64);
        s += __shfl_xor(s, 32, 64);  // all lanes: total for qrow base+l15
#pragma unroll
        for (int r = 0; r < 4; r++) {
            const float sv = __shfl(s, quad * 4 + r, 64);
            const float inv = 1.0f / sv;
            const int srow_o = qt * 128 + w * 32 + i * 16 + quad * 4 + r;
            bf16_t* orow = Aout + (size_t)(b * SEQ + srow_o) * DIM + hd * HD;
#pragma unroll
            for (int j = 0; j < 4; j++)
                orow[j * 16 + l15] = (bf16_t)(o[i][j][r] * inv);
        }
    }
}

// ---------------------------------------------------------------------------
extern "C" void kernel_launch(void* const* d_in, const int* in_sizes, int n_in,
                              void* d_out, int out_size, void* d_ws, size_t ws_size,
                              hipStream_t stream) {
    const float* x        = (const float*)d_in[0];
    const float* c_attn_w = (const float*)d_in[2];
    const float* c_attn_b = (const float*)d_in[3];
    const float* c_proj_w = (const float*)d_in[4];
    const float* c_proj_b = (const float*)d_in[5];
    float* out = (float*)d_out;

    char* ws = (char*)d_ws;
    bf16_t* xb     = (bf16_t*)ws; ws += (size_t)NB * SEQ * DIM * 2;
    bf16_t* wqkvT  = (bf16_t*)ws; ws += (size_t)3072 * 1024 * 2;
    bf16_t* wprojT = (bf16_t*)ws; ws += (size_t)1024 * 1024 * 2;
    bf16_t* Qb  = (bf16_t*)ws; ws += (size_t)NB * NH * SEQ * HD * 2;
    bf16_t* Kb  = (bf16_t*)ws; ws += (size_t)NB * NH * SEQ * HD * 2;
    // full 16 MB: Vt must NOT overlap Ab (attn reads Vt while writing Aout)
    bf16_t* Vtb = (bf16_t*)ws; ws += (size_t)NB * NH * SEQ * HD * 2;
    bf16_t* Ab  = (bf16_t*)ws; ws += (size_t)NB * SEQ * DIM * 2;

    prep<<<12288, 256, 0, stream>>>(x, xb, c_attn_w, wqkvT, c_proj_w, wprojT);

    // qkv projection: M=8192, N=3072, K=1024 — 256² 8-phase, 384 blocks
    gemm256_qkv<<<384, 512, 0, stream>>>(xb, wqkvT, c_attn_b, 1024,
                                         Qb, Kb, Vtb);

    // attention: 1024 one-q-tile blocks; bh-major -> id%8 == bh%8 (XCD/L2)
    attn1q<<<dim3(NB * NH, 16), 256, 0, stream>>>(Qb, Kb, Vtb, Ab);

    // output projection: M=8192, N=1024, K=1024, fp32 out
    gemm128<1><<<dim3(8, 64), 256, 0, stream>>>(Ab, wprojT, c_proj_b, 1024, out);
}